// Round 5
// baseline (835.848 us; speedup 1.0000x reference)
//
#include <hip/hip_runtime.h>
#include <cmath>

#define LN_EPS 1e-5f

typedef float  f32x4  __attribute__((ext_vector_type(4)));
typedef short  short8 __attribute__((ext_vector_type(8)));
typedef unsigned int uint4v __attribute__((ext_vector_type(4)));

// ws layout (uint offsets):
//   w1f  : uint4 [0,2560)        B-frag bf16 (5kt x 8nt x 64 lanes)
//   w2f  : uint4 [2560,4608)     (4kt x 8nt x 64)   -> uint [10240,18432)
//   sums : uint 18432..18437     (Sw,Sb,Sww,Swb,Sbb)
//   ctr  : uint 18440            (work counter, zeroed by prep every call)
//   emb16: uint 18448..          (NUM_TYPES*128 bf16 row-major; byte off 73792, 16B-aligned)
#define W1F_U4 2560
#define W2F_U4 2048
#define SUMS_U 18432
#define CTR_U  18440
#define EMB_U  18448

__device__ __forceinline__ unsigned short f32_bf16_rne(float f) {
    union { float f; unsigned u; } v; v.f = f;
    unsigned r = v.u + 0x7FFFu + ((v.u >> 16) & 1u);
    return (unsigned short)(r >> 16);
}

// exact-erf GELU via Abramowitz&Stegun 7.1.26 (|err| <= 1.5e-7)
__device__ __forceinline__ float gelu_f(float x) {
    float ax = fabsf(x);
    float a  = ax * 0.70710678118654752f;
    float t  = __builtin_amdgcn_rcpf(fmaf(0.3275911f, a, 1.0f));
    float p  = t * fmaf(t, fmaf(t, fmaf(t, fmaf(t, 1.061405429f, -1.453152027f),
                                        1.421413741f), -0.284496736f), 0.254829592f);
    float e  = __builtin_amdgcn_exp2f(-1.44269504089f * a * a);
    float E  = fmaf(-p, e, 1.0f);
    return 0.5f * fmaf(ax, E, x);
}

__global__ void prep_kernel(const float* __restrict__ w1, const float* __restrict__ w2,
                            const float* __restrict__ emb,
                            const float* __restrict__ tp_w, const float* __restrict__ tp_b,
                            unsigned* __restrict__ ws, int emb_pairs) {
    const int tid = blockIdx.x * 256 + threadIdx.x;
    const int NT  = gridDim.x * 256;
    uint4v* w1f = (uint4v*)ws;
    uint4v* w2f = w1f + W1F_U4;
    float*  sums = (float*)(ws + SUMS_U);
    unsigned* emb16 = ws + EMB_U;

    if (tid == 0) ws[CTR_U] = 0u;                      // work counter

    for (int i = tid; i < W1F_U4; i += NT) {
        const int lane = i & 63, nt = (i >> 6) & 7, kt = i >> 9;
        const int k0 = kt * 32 + (lane >> 4) * 8, n = nt * 16 + (lane & 15);
        uint4v r;
        #pragma unroll
        for (int j2 = 0; j2 < 4; ++j2) {
            unsigned lo = f32_bf16_rne(w1[(k0 + 2 * j2) * 128 + n]);
            unsigned hi = f32_bf16_rne(w1[(k0 + 2 * j2 + 1) * 128 + n]);
            r[j2] = lo | (hi << 16);
        }
        w1f[i] = r;
    }
    for (int i = tid; i < W2F_U4; i += NT) {
        const int lane = i & 63, nt = (i >> 6) & 7, kt = i >> 9;
        const int k0 = kt * 32 + (lane >> 4) * 8, n = nt * 16 + (lane & 15);
        uint4v r;
        #pragma unroll
        for (int j2 = 0; j2 < 4; ++j2) {
            unsigned lo = f32_bf16_rne(w2[(k0 + 2 * j2) * 128 + n]);
            unsigned hi = f32_bf16_rne(w2[(k0 + 2 * j2 + 1) * 128 + n]);
            r[j2] = lo | (hi << 16);
        }
        w2f[i] = r;
    }
    for (int i = tid; i < emb_pairs; i += NT) {
        unsigned lo = f32_bf16_rne(emb[2 * i]);
        unsigned hi = f32_bf16_rne(emb[2 * i + 1]);
        emb16[i] = lo | (hi << 16);
    }

    if (blockIdx.x == 0 && threadIdx.x < 64) {
        const int lane = threadIdx.x;
        float w = 0.f, bb = 0.f;
        if (lane < 32) { w = tp_w[lane]; bb = tp_b[lane]; }
        float s0 = w, s1 = bb, s2 = w * w, s3 = w * bb, s4 = bb * bb;
        #pragma unroll
        for (int m = 1; m < 64; m <<= 1) {
            s0 += __shfl_xor(s0, m); s1 += __shfl_xor(s1, m);
            s2 += __shfl_xor(s2, m); s3 += __shfl_xor(s3, m); s4 += __shfl_xor(s4, m);
        }
        if (lane == 0) { sums[0] = s0; sums[1] = s1; sums[2] = s2; sums[3] = s3; sums[4] = s4; }
    }
}

// Persistent 4-wave blocks; each wave pulls whole rows off an atomic queue.
// One 16-position m-tile at a time keeps live accumulators at 32 regs; all
// epilogue constants live in LDS so (256,4)=128-reg budget holds (16 waves/CU).
// R3 lesson: if this spills, WRITE_SIZE balloons -- that's the falsifier.
__global__ __launch_bounds__(256, 4) void encoder_mfma(
    const int*   __restrict__ tids,  const float* __restrict__ dates,
    const int*   __restrict__ lengths,
    const float* __restrict__ tp_w,  const float* __restrict__ tp_b,
    const float* __restrict__ tp_lnw,const float* __restrict__ tp_lnb,
    const float* __restrict__ b1,    const float* __restrict__ ln1w, const float* __restrict__ ln1b,
    const float* __restrict__ b2,    const float* __restrict__ ln2w, const float* __restrict__ ln2b,
    unsigned* __restrict__ ws, float* __restrict__ out, int B, int L)
{
    __shared__ float Sb1[128], Sl1w[128], Sl1b[128], Sb2[128], Sl2w[128], Sl2b[128];
    __shared__ float Stp[4][32];
    __shared__ float Ssum[8];
    __shared__ unsigned short a2[4][4][64][8];   // per-wave C->A transpose scratch (4 KB each)

    const int tid = threadIdx.x;
    if (tid < 128) {
        Sb1[tid] = b1[tid];  Sl1w[tid] = ln1w[tid]; Sl1b[tid] = ln1b[tid];
        Sb2[tid] = b2[tid];  Sl2w[tid] = ln2w[tid]; Sl2b[tid] = ln2b[tid];
    } else {
        const int t = tid - 128;
        if (t < 32) { Stp[0][t] = tp_w[t]; Stp[1][t] = tp_b[t]; Stp[2][t] = tp_lnw[t]; Stp[3][t] = tp_lnb[t]; }
        else if (t < 37) Ssum[t - 32] = ((const float*)(ws + SUMS_U))[t - 32];
    }
    __syncthreads();

    const int lane = tid & 63, w = tid >> 6;
    const int c = lane & 15, g = lane >> 4, h3 = c >> 3;
    const int srr = (c & 3) * 16 + g * 4 + (c >> 2);

    const uint4v* w1f = (const uint4v*)ws;
    const uint4v* w2f = w1f + W1F_U4;
    const unsigned short* emb16 = (const unsigned short*)(ws + EMB_U);
    unsigned* ctr = ws + CTR_U;

    const float Sw = Ssum[0], Sb = Ssum[1], Sww = Ssum[2], Swb = Ssum[3], Sbb = Ssum[4];

    for (;;) {
        unsigned row = 0;
        if (lane == 0) row = atomicAdd(ctr, 1u);
        row = (unsigned)__shfl((int)row, 0);
        if (row >= (unsigned)B) break;

        const int len = min(max(lengths[row], 0), L);
        if (len == 0) {
            for (int i = lane; i < 128; i += 64) out[row * 128u + i] = 0.f;
            continue;
        }
        const int base = (int)row * L;
        const int ntiles = (len + 15) >> 4;

        float pool[8];
        #pragma unroll
        for (int nt = 0; nt < 8; ++nt) pool[nt] = 0.f;

        for (int mt = 0; mt < ntiles; ++mt) {
            const int p  = mt * 16 + c;
            const int pc = min(p, len - 1);
            const int   id = tids[base + pc];
            const float dn = dates[base + pc] * (1.f / 1825.f);

            // ---- temporal A-frag (closed-form LN stats + GELU) ----
            short8 tf;
            {
                const float tm = fmaf(dn, Sw, Sb) * (1.f / 32.f);
                float tv = fmaf(dn * dn, Sww, fmaf(2.f * dn, Swb, Sbb)) * (1.f / 32.f) - tm * tm;
                const float trs = rsqrtf(fmaxf(tv, 0.f) + LN_EPS);
                uint4v r;
                #pragma unroll
                for (int j2 = 0; j2 < 4; ++j2) {
                    const int j0 = g * 8 + 2 * j2;
                    const float y0 = fmaf((fmaf(dn, Stp[0][j0],   Stp[1][j0])   - tm) * trs, Stp[2][j0],   Stp[3][j0]);
                    const float y1 = fmaf((fmaf(dn, Stp[0][j0+1], Stp[1][j0+1]) - tm) * trs, Stp[2][j0+1], Stp[3][j0+1]);
                    r[j2] = (unsigned)f32_bf16_rne(gelu_f(y0)) | ((unsigned)f32_bf16_rne(gelu_f(y1)) << 16);
                }
                union { uint4v u; short8 s; } cv; cv.u = r;
                tf = cv.s;
            }

            // ---- GEMM1: K=160 ----
            f32x4 acc[8];
            #pragma unroll
            for (int nt = 0; nt < 8; ++nt) acc[nt] = (f32x4){0.f, 0.f, 0.f, 0.f};
            #pragma unroll
            for (int kt = 0; kt < 5; ++kt) {
                short8 af;
                if (kt < 4) af = *(const short8*)(emb16 + id * 128 + kt * 32 + g * 8);
                else        af = tf;
                #pragma unroll
                for (int nt = 0; nt < 8; ++nt) {
                    const short8 bf = ((const short8*)w1f)[(kt * 8 + nt) * 64 + lane];
                    acc[nt] = __builtin_amdgcn_mfma_f32_16x16x32_bf16(af, bf, acc[nt], 0, 0, 0);
                }
            }

            // ---- epilogue 1: +b1, LN1, GELU -> a2 (swizzled, per-wave) ----
            #pragma unroll
            for (int r = 0; r < 4; ++r) {
                float v[8], s = 0.f, q = 0.f;
                #pragma unroll
                for (int nt = 0; nt < 8; ++nt) {
                    v[nt] = acc[nt][r] + Sb1[nt * 16 + c];
                    s += v[nt]; q = fmaf(v[nt], v[nt], q);
                }
                s += __shfl_xor(s, 1); q += __shfl_xor(q, 1);
                s += __shfl_xor(s, 2); q += __shfl_xor(q, 2);
                s += __shfl_xor(s, 4); q += __shfl_xor(q, 4);
                s += __shfl_xor(s, 8); q += __shfl_xor(q, 8);
                const float mean = s * (1.f / 128.f);
                const float var  = fmaxf(q * (1.f / 128.f) - mean * mean, 0.f);
                const float rstd = rsqrtf(var + LN_EPS);
                #pragma unroll
                for (int nt = 0; nt < 8; ++nt) {
                    const float y = fmaf((v[nt] - mean) * rstd, Sl1w[nt * 16 + c], Sl1b[nt * 16 + c]);
                    const unsigned short hv = f32_bf16_rne(gelu_f(y));
                    const int gk = (2 * nt + h3) & 3;
                    a2[w][nt >> 1][r * 16 + gk * 4 + g][c & 7] = hv;
                }
            }

            // ---- GEMM2: K=128 ----
            f32x4 acc2[8];
            #pragma unroll
            for (int nt = 0; nt < 8; ++nt) acc2[nt] = (f32x4){0.f, 0.f, 0.f, 0.f};
            #pragma unroll
            for (int kt2 = 0; kt2 < 4; ++kt2) {
                short8 af2;
                __builtin_memcpy(&af2, &a2[w][kt2][srr][0], 16);
                #pragma unroll
                for (int nt = 0; nt < 8; ++nt) {
                    const short8 bf = ((const short8*)w2f)[(kt2 * 8 + nt) * 64 + lane];
                    acc2[nt] = __builtin_amdgcn_mfma_f32_16x16x32_bf16(af2, bf, acc2[nt], 0, 0, 0);
                }
            }

            // ---- epilogue 2: +b2, LN2, mask, pool ----
            #pragma unroll
            for (int r = 0; r < 4; ++r) {
                float v[8], s = 0.f, q = 0.f;
                #pragma unroll
                for (int nt = 0; nt < 8; ++nt) {
                    v[nt] = acc2[nt][r] + Sb2[nt * 16 + c];
                    s += v[nt]; q = fmaf(v[nt], v[nt], q);
                }
                s += __shfl_xor(s, 1); q += __shfl_xor(q, 1);
                s += __shfl_xor(s, 2); q += __shfl_xor(q, 2);
                s += __shfl_xor(s, 4); q += __shfl_xor(q, 4);
                s += __shfl_xor(s, 8); q += __shfl_xor(q, 8);
                const float mean = s * (1.f / 128.f);
                const float var  = fmaxf(q * (1.f / 128.f) - mean * mean, 0.f);
                const float rstd = rsqrtf(var + LN_EPS);
                const int prow = mt * 16 + 4 * g + r;
                const float msk = (prow < len) ? 1.f : 0.f;
                #pragma unroll
                for (int nt = 0; nt < 8; ++nt) {
                    const float y = fmaf((v[nt] - mean) * rstd, Sl2w[nt * 16 + c], Sl2b[nt * 16 + c]);
                    pool[nt] = fmaf(y, msk, pool[nt]);
                }
            }
        }

        // row owned by this wave: reduce over g, plain store (no atomics)
        const float inv = 1.f / (float)len;
        #pragma unroll
        for (int nt = 0; nt < 8; ++nt) {
            float t = pool[nt];
            t += __shfl_xor(t, 16);
            t += __shfl_xor(t, 32);
            if (g == 0) out[row * 128u + nt * 16 + c] = t * inv;
        }
    }
}

extern "C" void kernel_launch(void* const* d_in, const int* in_sizes, int n_in,
                              void* d_out, int out_size, void* d_ws, size_t ws_size,
                              hipStream_t stream) {
    const int*   tids    = (const int*)  d_in[0];
    const float* dates   = (const float*)d_in[1];
    const int*   lengths = (const int*)  d_in[2];
    const float* emb     = (const float*)d_in[3];
    const float* tp_w    = (const float*)d_in[4];
    const float* tp_b    = (const float*)d_in[5];
    const float* tp_lnw  = (const float*)d_in[6];
    const float* tp_lnb  = (const float*)d_in[7];
    const float* w1      = (const float*)d_in[8];
    const float* b1      = (const float*)d_in[9];
    const float* ln1w    = (const float*)d_in[10];
    const float* ln1b    = (const float*)d_in[11];
    const float* w2      = (const float*)d_in[12];
    const float* b2      = (const float*)d_in[13];
    const float* ln2w    = (const float*)d_in[14];
    const float* ln2b    = (const float*)d_in[15];
    float* out = (float*)d_out;

    const int B = in_sizes[2];
    const int L = in_sizes[0] / B;
    const int emb_pairs = in_sizes[3] / 2;

    hipLaunchKernelGGL(prep_kernel, dim3(32), dim3(256), 0, stream,
                       w1, w2, emb, tp_w, tp_b, (unsigned*)d_ws, emb_pairs);
    hipLaunchKernelGGL(encoder_mfma, dim3(1024), dim3(256), 0, stream,
                       tids, dates, lengths, tp_w, tp_b, tp_lnw, tp_lnb,
                       b1, ln1w, ln1b, b2, ln2w, ln2b,
                       (unsigned*)d_ws, out, B, L);
}

// Round 6
// 584.917 us; speedup vs baseline: 1.4290x; 1.4290x over previous
//
#include <hip/hip_runtime.h>
#include <cmath>

#define LN_EPS 1e-5f

typedef float  f32x4  __attribute__((ext_vector_type(4)));
typedef short  short8 __attribute__((ext_vector_type(8)));
typedef unsigned int uint4v __attribute__((ext_vector_type(4)));

// ws layout (uint offsets):
//   w1f  : uint4 [0,2560)        B-frag bf16 (5kt x 8nt x 64 lanes)
//   w2f  : uint4 [2560,4608)     (4kt x 8nt x 64)   -> uint [10240,18432)
//   sums : uint 18432..18437     (Sw,Sb,Sww,Swb,Sbb)
//   ctr  : uint 18440            (work counter, zeroed by prep every call)
//   emb16: uint 18448..          (NUM_TYPES*128 bf16 row-major)
#define W1F_U4 2560
#define W2F_U4 2048
#define SUMS_U 18432
#define CTR_U  18440
#define EMB_U  18448

__device__ __forceinline__ unsigned short f32_bf16_rne(float f) {
    union { float f; unsigned u; } v; v.f = f;
    unsigned r = v.u + 0x7FFFu + ((v.u >> 16) & 1u);
    return (unsigned short)(r >> 16);
}

// exact-erf GELU via Abramowitz&Stegun 7.1.26 (|err| <= 1.5e-7)
__device__ __forceinline__ float gelu_f(float x) {
    float ax = fabsf(x);
    float a  = ax * 0.70710678118654752f;
    float t  = __builtin_amdgcn_rcpf(fmaf(0.3275911f, a, 1.0f));
    float p  = t * fmaf(t, fmaf(t, fmaf(t, fmaf(t, 1.061405429f, -1.453152027f),
                                        1.421413741f), -0.284496736f), 0.254829592f);
    float e  = __builtin_amdgcn_exp2f(-1.44269504089f * a * a);
    float E  = fmaf(-p, e, 1.0f);
    return 0.5f * fmaf(ax, E, x);
}

__global__ void prep_kernel(const float* __restrict__ w1, const float* __restrict__ w2,
                            const float* __restrict__ emb,
                            const float* __restrict__ tp_w, const float* __restrict__ tp_b,
                            unsigned* __restrict__ ws, int emb_pairs) {
    const int tid = blockIdx.x * 256 + threadIdx.x;
    const int NT  = gridDim.x * 256;
    uint4v* w1f = (uint4v*)ws;
    uint4v* w2f = w1f + W1F_U4;
    float*  sums = (float*)(ws + SUMS_U);
    unsigned* emb16 = ws + EMB_U;

    if (tid == 0) ws[CTR_U] = 0u;                      // work counter

    for (int i = tid; i < W1F_U4; i += NT) {
        const int lane = i & 63, nt = (i >> 6) & 7, kt = i >> 9;
        const int k0 = kt * 32 + (lane >> 4) * 8, n = nt * 16 + (lane & 15);
        uint4v r;
        #pragma unroll
        for (int j2 = 0; j2 < 4; ++j2) {
            unsigned lo = f32_bf16_rne(w1[(k0 + 2 * j2) * 128 + n]);
            unsigned hi = f32_bf16_rne(w1[(k0 + 2 * j2 + 1) * 128 + n]);
            r[j2] = lo | (hi << 16);
        }
        w1f[i] = r;
    }
    for (int i = tid; i < W2F_U4; i += NT) {
        const int lane = i & 63, nt = (i >> 6) & 7, kt = i >> 9;
        const int k0 = kt * 32 + (lane >> 4) * 8, n = nt * 16 + (lane & 15);
        uint4v r;
        #pragma unroll
        for (int j2 = 0; j2 < 4; ++j2) {
            unsigned lo = f32_bf16_rne(w2[(k0 + 2 * j2) * 128 + n]);
            unsigned hi = f32_bf16_rne(w2[(k0 + 2 * j2 + 1) * 128 + n]);
            r[j2] = lo | (hi << 16);
        }
        w2f[i] = r;
    }
    for (int i = tid; i < emb_pairs; i += NT) {
        unsigned lo = f32_bf16_rne(emb[2 * i]);
        unsigned hi = f32_bf16_rne(emb[2 * i + 1]);
        emb16[i] = lo | (hi << 16);
    }

    if (blockIdx.x == 0 && threadIdx.x < 64) {
        const int lane = threadIdx.x;
        float w = 0.f, bb = 0.f;
        if (lane < 32) { w = tp_w[lane]; bb = tp_b[lane]; }
        float s0 = w, s1 = bb, s2 = w * w, s3 = w * bb, s4 = bb * bb;
        #pragma unroll
        for (int m = 1; m < 64; m <<= 1) {
            s0 += __shfl_xor(s0, m); s1 += __shfl_xor(s1, m);
            s2 += __shfl_xor(s2, m); s3 += __shfl_xor(s3, m); s4 += __shfl_xor(s4, m);
        }
        if (lane == 0) { sums[0] = s0; sums[1] = s1; sums[2] = s2; sums[3] = s3; sums[4] = s4; }
    }
}

// Persistent 4-wave blocks (grid 512); each wave pulls whole rows off an atomic
// queue and owns them (plain stores, no out-zeroing). w1 B-frags staged in LDS
// (40 KB) to cut the per-tile frag-fetch latency from ~300 cyc (L2) to ~40 cyc;
// w2 frags stay in global/L2 so spare VGPRs can register-cache them.
// launch_bounds(256,2): 256-reg/wave budget. R3+R5 lesson: anything tighter
// spills the accumulators (WRITE_SIZE balloons) -- that is the falsifier.
__global__ __launch_bounds__(256, 2) void encoder_mfma(
    const int*   __restrict__ tids,  const float* __restrict__ dates,
    const int*   __restrict__ lengths,
    const float* __restrict__ tp_w,  const float* __restrict__ tp_b,
    const float* __restrict__ tp_lnw,const float* __restrict__ tp_lnb,
    const float* __restrict__ b1,    const float* __restrict__ ln1w, const float* __restrict__ ln1b,
    const float* __restrict__ b2,    const float* __restrict__ ln2w, const float* __restrict__ ln2b,
    unsigned* __restrict__ ws, float* __restrict__ out, int B, int L)
{
    __shared__ __attribute__((aligned(16))) uint4v Sw1[W1F_U4];           // 40960 B
    __shared__ __attribute__((aligned(16))) unsigned short a2[4][4][64][8]; // 16384 B

    const int tid = threadIdx.x;
    for (int i = tid; i < W1F_U4; i += 256) Sw1[i] = ((const uint4v*)ws)[i];
    __syncthreads();                                   // only barrier in the kernel

    const int lane = tid & 63, w = tid >> 6;
    const int c = lane & 15, g = lane >> 4, h3 = c >> 3;
    const int srr = (c & 3) * 16 + g * 4 + (c >> 2);   // swizzled a2 read row

    const uint4v* w2f = ((const uint4v*)ws) + W1F_U4;
    const unsigned short* emb16 = (const unsigned short*)(ws + EMB_U);
    unsigned* ctr = ws + CTR_U;
    const float* sums = (const float*)(ws + SUMS_U);
    const float Sw = sums[0], Sb = sums[1], Sww = sums[2], Swb = sums[3], Sbb = sums[4];

    // all row-invariant constants in registers (once per wave, ~80 regs)
    float tw[8], tb[8], tlw[8], tlb[8];
    #pragma unroll
    for (int jj = 0; jj < 8; ++jj) {
        tw[jj]  = tp_w[g * 8 + jj];   tb[jj]  = tp_b[g * 8 + jj];
        tlw[jj] = tp_lnw[g * 8 + jj]; tlb[jj] = tp_lnb[g * 8 + jj];
    }
    float bb1[8], l1w[8], l1b[8], bb2[8], l2w[8], l2b[8];
    #pragma unroll
    for (int nt = 0; nt < 8; ++nt) {
        bb1[nt] = b1[nt * 16 + c]; l1w[nt] = ln1w[nt * 16 + c]; l1b[nt] = ln1b[nt * 16 + c];
        bb2[nt] = b2[nt * 16 + c]; l2w[nt] = ln2w[nt * 16 + c]; l2b[nt] = ln2b[nt * 16 + c];
    }

    for (;;) {
        int row = 0;
        if (lane == 0) row = (int)atomicAdd(ctr, 1u);
        row = __shfl(row, 0);
        if (row >= B) break;

        const int len = min(max(lengths[row], 0), L);
        if (len == 0) {
            for (int i = lane; i < 128; i += 64) out[row * 128 + i] = 0.f;
            continue;
        }
        const int base = row * L;
        const int ntiles = (len + 15) >> 4;

        float pool[8];
        #pragma unroll
        for (int nt = 0; nt < 8; ++nt) pool[nt] = 0.f;

        for (int mt = 0; mt < ntiles; ++mt) {
            const int p  = mt * 16 + c;
            const int pc = min(p, len - 1);
            const int   id = tids[base + pc];
            const float dn = dates[base + pc] * (1.f / 1825.f);

            // ---- temporal A-frag (closed-form LN stats + GELU), constants in regs ----
            short8 tf;
            {
                const float tm = fmaf(dn, Sw, Sb) * (1.f / 32.f);
                float tv = fmaf(dn * dn, Sww, fmaf(2.f * dn, Swb, Sbb)) * (1.f / 32.f) - tm * tm;
                const float trs = rsqrtf(fmaxf(tv, 0.f) + LN_EPS);
                uint4v r;
                #pragma unroll
                for (int j2 = 0; j2 < 4; ++j2) {
                    const float y0 = fmaf((fmaf(dn, tw[2*j2],   tb[2*j2])   - tm) * trs, tlw[2*j2],   tlb[2*j2]);
                    const float y1 = fmaf((fmaf(dn, tw[2*j2+1], tb[2*j2+1]) - tm) * trs, tlw[2*j2+1], tlb[2*j2+1]);
                    r[j2] = (unsigned)f32_bf16_rne(gelu_f(y0)) | ((unsigned)f32_bf16_rne(gelu_f(y1)) << 16);
                }
                union { uint4v u; short8 s; } cv; cv.u = r;
                tf = cv.s;
            }

            // ---- GEMM1: K=160, B-frags from LDS ----
            f32x4 acc[8];
            #pragma unroll
            for (int nt = 0; nt < 8; ++nt) acc[nt] = (f32x4){0.f, 0.f, 0.f, 0.f};
            #pragma unroll
            for (int kt = 0; kt < 5; ++kt) {
                short8 af;
                if (kt < 4) af = *(const short8*)(emb16 + id * 128 + kt * 32 + g * 8);
                else        af = tf;
                #pragma unroll
                for (int nt = 0; nt < 8; ++nt) {
                    short8 bf;
                    __builtin_memcpy(&bf, &Sw1[(kt * 8 + nt) * 64 + lane], 16);
                    acc[nt] = __builtin_amdgcn_mfma_f32_16x16x32_bf16(af, bf, acc[nt], 0, 0, 0);
                }
            }

            // ---- epilogue 1: +b1, LN1, GELU -> a2 (swizzled, per-wave) ----
            #pragma unroll
            for (int r = 0; r < 4; ++r) {
                float v[8], s = 0.f, q = 0.f;
                #pragma unroll
                for (int nt = 0; nt < 8; ++nt) {
                    v[nt] = acc[nt][r] + bb1[nt];
                    s += v[nt]; q = fmaf(v[nt], v[nt], q);
                }
                s += __shfl_xor(s, 1); q += __shfl_xor(q, 1);
                s += __shfl_xor(s, 2); q += __shfl_xor(q, 2);
                s += __shfl_xor(s, 4); q += __shfl_xor(q, 4);
                s += __shfl_xor(s, 8); q += __shfl_xor(q, 8);
                const float mean = s * (1.f / 128.f);
                const float var  = fmaxf(q * (1.f / 128.f) - mean * mean, 0.f);
                const float rstd = rsqrtf(var + LN_EPS);
                #pragma unroll
                for (int nt = 0; nt < 8; ++nt) {
                    const float y = fmaf((v[nt] - mean) * rstd, l1w[nt], l1b[nt]);
                    const unsigned short hv = f32_bf16_rne(gelu_f(y));
                    const int gk = (2 * nt + h3) & 3;
                    a2[w][nt >> 1][r * 16 + gk * 4 + g][c & 7] = hv;
                }
            }

            // ---- GEMM2: K=128, B-frags from global/L2 (loop-invariant -> reg-cacheable) ----
            f32x4 acc2[8];
            #pragma unroll
            for (int nt = 0; nt < 8; ++nt) acc2[nt] = (f32x4){0.f, 0.f, 0.f, 0.f};
            #pragma unroll
            for (int kt2 = 0; kt2 < 4; ++kt2) {
                short8 af2;
                __builtin_memcpy(&af2, &a2[w][kt2][srr][0], 16);
                #pragma unroll
                for (int nt = 0; nt < 8; ++nt) {
                    const short8 bf = ((const short8*)w2f)[(kt2 * 8 + nt) * 64 + lane];
                    acc2[nt] = __builtin_amdgcn_mfma_f32_16x16x32_bf16(af2, bf, acc2[nt], 0, 0, 0);
                }
            }

            // ---- epilogue 2: +b2, LN2, mask, pool ----
            #pragma unroll
            for (int r = 0; r < 4; ++r) {
                float v[8], s = 0.f, q = 0.f;
                #pragma unroll
                for (int nt = 0; nt < 8; ++nt) {
                    v[nt] = acc2[nt][r] + bb2[nt];
                    s += v[nt]; q = fmaf(v[nt], v[nt], q);
                }
                s += __shfl_xor(s, 1); q += __shfl_xor(q, 1);
                s += __shfl_xor(s, 2); q += __shfl_xor(q, 2);
                s += __shfl_xor(s, 4); q += __shfl_xor(q, 4);
                s += __shfl_xor(s, 8); q += __shfl_xor(q, 8);
                const float mean = s * (1.f / 128.f);
                const float var  = fmaxf(q * (1.f / 128.f) - mean * mean, 0.f);
                const float rstd = rsqrtf(var + LN_EPS);
                const int prow = mt * 16 + 4 * g + r;
                const float msk = (prow < len) ? 1.f : 0.f;
                #pragma unroll
                for (int nt = 0; nt < 8; ++nt) {
                    const float y = fmaf((v[nt] - mean) * rstd, l2w[nt], l2b[nt]);
                    pool[nt] = fmaf(y, msk, pool[nt]);
                }
            }
        }

        // row owned by this wave: reduce over g, plain store
        const float inv = 1.f / (float)len;
        #pragma unroll
        for (int nt = 0; nt < 8; ++nt) {
            float t = pool[nt];
            t += __shfl_xor(t, 16);
            t += __shfl_xor(t, 32);
            if (g == 0) out[row * 128 + nt * 16 + c] = t * inv;
        }
    }
}

extern "C" void kernel_launch(void* const* d_in, const int* in_sizes, int n_in,
                              void* d_out, int out_size, void* d_ws, size_t ws_size,
                              hipStream_t stream) {
    const int*   tids    = (const int*)  d_in[0];
    const float* dates   = (const float*)d_in[1];
    const int*   lengths = (const int*)  d_in[2];
    const float* emb     = (const float*)d_in[3];
    const float* tp_w    = (const float*)d_in[4];
    const float* tp_b    = (const float*)d_in[5];
    const float* tp_lnw  = (const float*)d_in[6];
    const float* tp_lnb  = (const float*)d_in[7];
    const float* w1      = (const float*)d_in[8];
    const float* b1      = (const float*)d_in[9];
    const float* ln1w    = (const float*)d_in[10];
    const float* ln1b    = (const float*)d_in[11];
    const float* w2      = (const float*)d_in[12];
    const float* b2      = (const float*)d_in[13];
    const float* ln2w    = (const float*)d_in[14];
    const float* ln2b    = (const float*)d_in[15];
    float* out = (float*)d_out;

    const int B = in_sizes[2];
    const int L = in_sizes[0] / B;
    const int emb_pairs = in_sizes[3] / 2;

    hipLaunchKernelGGL(prep_kernel, dim3(32), dim3(256), 0, stream,
                       w1, w2, emb, tp_w, tp_b, (unsigned*)d_ws, emb_pairs);
    hipLaunchKernelGGL(encoder_mfma, dim3(512), dim3(256), 0, stream,
                       tids, dates, lengths, tp_w, tp_b, tp_lnw, tp_lnb,
                       b1, ln1w, ln1b, b2, ln2w, ln2b,
                       (unsigned*)d_ws, out, B, L);
}

// Round 7
// 570.506 us; speedup vs baseline: 1.4651x; 1.0253x over previous
//
#include <hip/hip_runtime.h>
#include <cmath>

#define LN_EPS 1e-5f

typedef float  f32x4  __attribute__((ext_vector_type(4)));
typedef short  short8 __attribute__((ext_vector_type(8)));
typedef unsigned int uint4v __attribute__((ext_vector_type(4)));

// ws layout (uint offsets):
//   w1f  : uint4 [0,2560)        B-frag bf16 (5kt x 8nt x 64 lanes)
//   w2f  : uint4 [2560,4608)     (4kt x 8nt x 64)   -> uint [10240,18432)
//   sums : uint 18432..18437     (Sw,Sb,Sww,Swb,Sbb)
//   ctr  : uint 18440            (work counter, zeroed by prep every call)
//   emb16: uint 18448..          (NUM_TYPES*128 bf16 row-major)
#define W1F_U4 2560
#define W2F_U4 2048
#define SUMS_U 18432
#define CTR_U  18440
#define EMB_U  18448

__device__ __forceinline__ unsigned short f32_bf16_rne(float f) {
    union { float f; unsigned u; } v; v.f = f;
    unsigned r = v.u + 0x7FFFu + ((v.u >> 16) & 1u);
    return (unsigned short)(r >> 16);
}

// exact-erf GELU via Abramowitz&Stegun 7.1.26 (|err| <= 1.5e-7)
__device__ __forceinline__ float gelu_f(float x) {
    float ax = fabsf(x);
    float a  = ax * 0.70710678118654752f;
    float t  = __builtin_amdgcn_rcpf(fmaf(0.3275911f, a, 1.0f));
    float p  = t * fmaf(t, fmaf(t, fmaf(t, fmaf(t, 1.061405429f, -1.453152027f),
                                        1.421413741f), -0.284496736f), 0.254829592f);
    float e  = __builtin_amdgcn_exp2f(-1.44269504089f * a * a);
    float E  = fmaf(-p, e, 1.0f);
    return 0.5f * fmaf(ax, E, x);
}

__global__ void prep_kernel(const float* __restrict__ w1, const float* __restrict__ w2,
                            const float* __restrict__ emb,
                            const float* __restrict__ tp_w, const float* __restrict__ tp_b,
                            unsigned* __restrict__ ws, int emb_pairs) {
    const int tid = blockIdx.x * 256 + threadIdx.x;
    const int NT  = gridDim.x * 256;
    uint4v* w1f = (uint4v*)ws;
    uint4v* w2f = w1f + W1F_U4;
    float*  sums = (float*)(ws + SUMS_U);
    unsigned* emb16 = ws + EMB_U;

    if (tid == 0) ws[CTR_U] = 0u;                      // work counter

    for (int i = tid; i < W1F_U4; i += NT) {
        const int lane = i & 63, nt = (i >> 6) & 7, kt = i >> 9;
        const int k0 = kt * 32 + (lane >> 4) * 8, n = nt * 16 + (lane & 15);
        uint4v r;
        #pragma unroll
        for (int j2 = 0; j2 < 4; ++j2) {
            unsigned lo = f32_bf16_rne(w1[(k0 + 2 * j2) * 128 + n]);
            unsigned hi = f32_bf16_rne(w1[(k0 + 2 * j2 + 1) * 128 + n]);
            r[j2] = lo | (hi << 16);
        }
        w1f[i] = r;
    }
    for (int i = tid; i < W2F_U4; i += NT) {
        const int lane = i & 63, nt = (i >> 6) & 7, kt = i >> 9;
        const int k0 = kt * 32 + (lane >> 4) * 8, n = nt * 16 + (lane & 15);
        uint4v r;
        #pragma unroll
        for (int j2 = 0; j2 < 4; ++j2) {
            unsigned lo = f32_bf16_rne(w2[(k0 + 2 * j2) * 128 + n]);
            unsigned hi = f32_bf16_rne(w2[(k0 + 2 * j2 + 1) * 128 + n]);
            r[j2] = lo | (hi << 16);
        }
        w2f[i] = r;
    }
    for (int i = tid; i < emb_pairs; i += NT) {
        unsigned lo = f32_bf16_rne(emb[2 * i]);
        unsigned hi = f32_bf16_rne(emb[2 * i + 1]);
        emb16[i] = lo | (hi << 16);
    }

    if (blockIdx.x == 0 && threadIdx.x < 64) {
        const int lane = threadIdx.x;
        float w = 0.f, bb = 0.f;
        if (lane < 32) { w = tp_w[lane]; bb = tp_b[lane]; }
        float s0 = w, s1 = bb, s2 = w * w, s3 = w * bb, s4 = bb * bb;
        #pragma unroll
        for (int m = 1; m < 64; m <<= 1) {
            s0 += __shfl_xor(s0, m); s1 += __shfl_xor(s1, m);
            s2 += __shfl_xor(s2, m); s3 += __shfl_xor(s3, m); s4 += __shfl_xor(s4, m);
        }
        if (lane == 0) { sums[0] = s0; sums[1] = s1; sums[2] = s2; sums[3] = s3; sums[4] = s4; }
    }
}

// Persistent 4-wave blocks (grid 512); atomic row queue; row owned by one wave.
// Register ledger (the R5/R6 lesson -- unified file, 256/wave at 2 waves/SIMD):
//   w2 frags DELIBERATELY register-resident:  128 VGPR (short8 w2r[32])
//   accumulators (one GEMM live at a time):    64
//   pool + transients:                        ~45
//   EVERYTHING else (bias/ln/tp consts) lives in LDS, permuted so each lane's
//   8 values are 32 contiguous broadcast bytes (2x ds_read_b128, no conflict).
//   If the allocator runs tight it re-reads LDS instead of spilling to scratch.
// Falsifier: WRITE_SIZE >> 10 MB means it spilled anyway.
__global__ __launch_bounds__(256, 2) void encoder_mfma(
    const int*   __restrict__ tids,  const float* __restrict__ dates,
    const int*   __restrict__ lengths,
    const float* __restrict__ tp_w,  const float* __restrict__ tp_b,
    const float* __restrict__ tp_lnw,const float* __restrict__ tp_lnb,
    const float* __restrict__ b1,    const float* __restrict__ ln1w, const float* __restrict__ ln1b,
    const float* __restrict__ b2,    const float* __restrict__ ln2w, const float* __restrict__ ln2b,
    unsigned* __restrict__ ws, float* __restrict__ out, int B, int L)
{
    __shared__ __attribute__((aligned(16))) uint4v Sw1[W1F_U4];             // 40960 B
    __shared__ __attribute__((aligned(16))) unsigned short a2[4][4][64][8]; // 16384 B
    // permuted epilogue constants: index [c*8 + nt]  (orig n = nt*16 + c)
    __shared__ __attribute__((aligned(16))) float Cb1[128], Cl1w[128], Cl1b[128];
    __shared__ __attribute__((aligned(16))) float Cb2[128], Cl2w[128], Cl2b[128];
    __shared__ __attribute__((aligned(16))) float Ctp[4][32];
    __shared__ float Csum[8];

    const int tid = threadIdx.x;
    #pragma unroll
    for (int i = 0; i < 10; ++i) Sw1[tid + i * 256] = ((const uint4v*)ws)[tid + i * 256];
    if (tid < 128) {
        const int cc = tid & 15, nn = tid >> 4, pi = cc * 8 + nn;
        Cb1[pi] = b1[tid];  Cl1w[pi] = ln1w[tid]; Cl1b[pi] = ln1b[tid];
        Cb2[pi] = b2[tid];  Cl2w[pi] = ln2w[tid]; Cl2b[pi] = ln2b[tid];
    } else {
        const int t = tid - 128;
        if (t < 32) { Ctp[0][t] = tp_w[t]; Ctp[1][t] = tp_b[t]; Ctp[2][t] = tp_lnw[t]; Ctp[3][t] = tp_lnb[t]; }
        else if (t < 37) Csum[t - 32] = ((const float*)(ws + SUMS_U))[t - 32];
    }
    __syncthreads();

    const int lane = tid & 63, w = tid >> 6;
    const int c = lane & 15, g = lane >> 4, h3 = c >> 3;
    const int srr = (c & 3) * 16 + g * 4 + (c >> 2);   // swizzled a2 read row

    const unsigned short* emb16 = (const unsigned short*)(ws + EMB_U);
    unsigned* ctr = ws + CTR_U;

    // ---- manual hoist: w2 B-frags into 128 registers, once per wave ----
    short8 w2r[32];
    {
        const uint4v* w2f = ((const uint4v*)ws) + W1F_U4;
        #pragma unroll
        for (int i = 0; i < 32; ++i) {
            union { uint4v u; short8 s; } cv;
            cv.u = w2f[i * 64 + lane];
            w2r[i] = cv.s;
        }
    }

    const float Sw = Csum[0], Sb = Csum[1], Sww = Csum[2], Swb = Csum[3], Sbb = Csum[4];

    for (;;) {
        int row = 0;
        if (lane == 0) row = (int)atomicAdd(ctr, 1u);
        row = __shfl(row, 0);
        if (row >= B) break;

        const int len = min(max(lengths[row], 0), L);
        if (len == 0) {
            for (int i = lane; i < 128; i += 64) out[row * 128 + i] = 0.f;
            continue;
        }
        const int base = row * L;
        const int ntiles = (len + 15) >> 4;

        float pool[8];
        #pragma unroll
        for (int nt = 0; nt < 8; ++nt) pool[nt] = 0.f;

        for (int mt = 0; mt < ntiles; ++mt) {
            const int p  = mt * 16 + c;
            const int pc = min(p, len - 1);
            const int   id = tids[base + pc];
            const float dn = dates[base + pc] * (1.f / 1825.f);

            // ---- temporal A-frag (closed-form LN stats + GELU) ----
            short8 tf;
            {
                const float tm = fmaf(dn, Sw, Sb) * (1.f / 32.f);
                float tv = fmaf(dn * dn, Sww, fmaf(2.f * dn, Swb, Sbb)) * (1.f / 32.f) - tm * tm;
                const float trs = rsqrtf(fmaxf(tv, 0.f) + LN_EPS);
                uint4v r;
                #pragma unroll
                for (int j2 = 0; j2 < 4; ++j2) {
                    const int j0 = g * 8 + 2 * j2;
                    const float y0 = fmaf((fmaf(dn, Ctp[0][j0],   Ctp[1][j0])   - tm) * trs, Ctp[2][j0],   Ctp[3][j0]);
                    const float y1 = fmaf((fmaf(dn, Ctp[0][j0+1], Ctp[1][j0+1]) - tm) * trs, Ctp[2][j0+1], Ctp[3][j0+1]);
                    r[j2] = (unsigned)f32_bf16_rne(gelu_f(y0)) | ((unsigned)f32_bf16_rne(gelu_f(y1)) << 16);
                }
                union { uint4v u; short8 s; } cv; cv.u = r;
                tf = cv.s;
            }

            // ---- GEMM1: K=160, B-frags from LDS ----
            f32x4 acc[8];
            #pragma unroll
            for (int nt = 0; nt < 8; ++nt) acc[nt] = (f32x4){0.f, 0.f, 0.f, 0.f};
            #pragma unroll
            for (int kt = 0; kt < 5; ++kt) {
                short8 af;
                if (kt < 4) af = *(const short8*)(emb16 + id * 128 + kt * 32 + g * 8);
                else        af = tf;
                #pragma unroll
                for (int nt = 0; nt < 8; ++nt) {
                    short8 bf;
                    __builtin_memcpy(&bf, &Sw1[(kt * 8 + nt) * 64 + lane], 16);
                    acc[nt] = __builtin_amdgcn_mfma_f32_16x16x32_bf16(af, bf, acc[nt], 0, 0, 0);
                }
            }

            // ---- epilogue 1: +b1, LN1, GELU -> a2 (swizzled) ----
            #pragma unroll
            for (int r = 0; r < 4; ++r) {
                float v[8], s = 0.f, q = 0.f;
                #pragma unroll
                for (int nt = 0; nt < 8; ++nt) {
                    v[nt] = acc[nt][r] + Cb1[c * 8 + nt];
                    s += v[nt]; q = fmaf(v[nt], v[nt], q);
                }
                s += __shfl_xor(s, 1); q += __shfl_xor(q, 1);
                s += __shfl_xor(s, 2); q += __shfl_xor(q, 2);
                s += __shfl_xor(s, 4); q += __shfl_xor(q, 4);
                s += __shfl_xor(s, 8); q += __shfl_xor(q, 8);
                const float mean = s * (1.f / 128.f);
                const float var  = fmaxf(q * (1.f / 128.f) - mean * mean, 0.f);
                const float rstd = rsqrtf(var + LN_EPS);
                #pragma unroll
                for (int nt = 0; nt < 8; ++nt) {
                    const float y = fmaf((v[nt] - mean) * rstd, Cl1w[c * 8 + nt], Cl1b[c * 8 + nt]);
                    const unsigned short hv = f32_bf16_rne(gelu_f(y));
                    const int gk = (2 * nt + h3) & 3;
                    a2[w][nt >> 1][r * 16 + gk * 4 + g][c & 7] = hv;
                }
            }

            // ---- GEMM2: K=128, B-frags from registers ----
            f32x4 acc2[8];
            #pragma unroll
            for (int nt = 0; nt < 8; ++nt) acc2[nt] = (f32x4){0.f, 0.f, 0.f, 0.f};
            #pragma unroll
            for (int kt2 = 0; kt2 < 4; ++kt2) {
                short8 af2;
                __builtin_memcpy(&af2, &a2[w][kt2][srr][0], 16);
                #pragma unroll
                for (int nt = 0; nt < 8; ++nt)
                    acc2[nt] = __builtin_amdgcn_mfma_f32_16x16x32_bf16(af2, w2r[kt2 * 8 + nt], acc2[nt], 0, 0, 0);
            }

            // ---- epilogue 2: +b2, LN2, mask, pool ----
            #pragma unroll
            for (int r = 0; r < 4; ++r) {
                float v[8], s = 0.f, q = 0.f;
                #pragma unroll
                for (int nt = 0; nt < 8; ++nt) {
                    v[nt] = acc2[nt][r] + Cb2[c * 8 + nt];
                    s += v[nt]; q = fmaf(v[nt], v[nt], q);
                }
                s += __shfl_xor(s, 1); q += __shfl_xor(q, 1);
                s += __shfl_xor(s, 2); q += __shfl_xor(q, 2);
                s += __shfl_xor(s, 4); q += __shfl_xor(q, 4);
                s += __shfl_xor(s, 8); q += __shfl_xor(q, 8);
                const float mean = s * (1.f / 128.f);
                const float var  = fmaxf(q * (1.f / 128.f) - mean * mean, 0.f);
                const float rstd = rsqrtf(var + LN_EPS);
                const int prow = mt * 16 + 4 * g + r;
                const float msk = (prow < len) ? 1.f : 0.f;
                #pragma unroll
                for (int nt = 0; nt < 8; ++nt) {
                    const float y = fmaf((v[nt] - mean) * rstd, Cl2w[c * 8 + nt], Cl2b[c * 8 + nt]);
                    pool[nt] = fmaf(y, msk, pool[nt]);
                }
            }
        }

        // row owned by this wave: reduce over g, plain store
        const float inv = 1.f / (float)len;
        #pragma unroll
        for (int nt = 0; nt < 8; ++nt) {
            float t = pool[nt];
            t += __shfl_xor(t, 16);
            t += __shfl_xor(t, 32);
            if (g == 0) out[row * 128 + nt * 16 + c] = t * inv;
        }
    }
}

extern "C" void kernel_launch(void* const* d_in, const int* in_sizes, int n_in,
                              void* d_out, int out_size, void* d_ws, size_t ws_size,
                              hipStream_t stream) {
    const int*   tids    = (const int*)  d_in[0];
    const float* dates   = (const float*)d_in[1];
    const int*   lengths = (const int*)  d_in[2];
    const float* emb     = (const float*)d_in[3];
    const float* tp_w    = (const float*)d_in[4];
    const float* tp_b    = (const float*)d_in[5];
    const float* tp_lnw  = (const float*)d_in[6];
    const float* tp_lnb  = (const float*)d_in[7];
    const float* w1      = (const float*)d_in[8];
    const float* b1      = (const float*)d_in[9];
    const float* ln1w    = (const float*)d_in[10];
    const float* ln1b    = (const float*)d_in[11];
    const float* w2      = (const float*)d_in[12];
    const float* b2      = (const float*)d_in[13];
    const float* ln2w    = (const float*)d_in[14];
    const float* ln2b    = (const float*)d_in[15];
    float* out = (float*)d_out;

    const int B = in_sizes[2];
    const int L = in_sizes[0] / B;
    const int emb_pairs = in_sizes[3] / 2;

    hipLaunchKernelGGL(prep_kernel, dim3(32), dim3(256), 0, stream,
                       w1, w2, emb, tp_w, tp_b, (unsigned*)d_ws, emb_pairs);
    hipLaunchKernelGGL(encoder_mfma, dim3(512), dim3(256), 0, stream,
                       tids, dates, lengths, tp_w, tp_b, tp_lnw, tp_lnb,
                       b1, ln1w, ln1b, b2, ln2w, ln2b,
                       (unsigned*)d_ws, out, B, L);
}